// Round 6
// baseline (59.305 us; speedup 1.0000x reference)
//
#include <hip/hip_runtime.h>
#include <hip/hip_bf16.h>

#define NN 96
#define DD 64
#define HH 256
#define H2 128

// ---------------- Kernel A: projections (round-2 proven form) ----------------
__global__ __launch_bounds__(256) void proj_kernel(
    const float* __restrict__ X, const float* __restrict__ W1, const float* __restrict__ b1,
    const float* __restrict__ V1, const float* __restrict__ c1,
    float* __restrict__ pi, float* __restrict__ pj,
    float* __restrict__ ta, float* __restrict__ tb, float* __restrict__ tcT)
{
    const int i = blockIdx.x;
    const int h = threadIdx.x;          // 0..255
    __shared__ float xs[DD];
    if (h < DD) xs[h] = X[i*DD + h];
    __syncthreads();
    float aPi = 0.f, aPj = 0.f, aTa = 0.f, aTb = 0.f, aTc = 0.f;
    #pragma unroll 8
    for (int d = 0; d < DD; ++d) {
        const float x = xs[d];
        aPi = fmaf(x, W1[d*HH + h],          aPi);
        aPj = fmaf(x, W1[(DD + d)*HH + h],   aPj);
        aTa = fmaf(x, V1[d*HH + h],          aTa);
        aTb = fmaf(x, V1[(DD + d)*HH + h],   aTb);
        aTc = fmaf(x, V1[(2*DD + d)*HH + h], aTc);
    }
    pi[i*HH + h] = aPi + b1[h];
    pj[i*HH + h] = aPj;
    ta[i*HH + h] = aTa + c1[h];
    tb[i*HH + h] = aTb;
    tcT[h*NN + i] = aTc;
}

// ---------------- Kernel B: causal [96,96] ----------------
// R4-inner resurrected for a clean A/B: grid (96,6), 16 j per block.
// 256 threads: qt = t>>6 (h-quarter per wave), jq = (t&63)>>4, cc = t&15
// (owns 8 channels cc+16u). One b128 broadcast feeds 32 FMA -> DS pipe
// 27.6k -> 6.9k cy/CU. unroll 4 gives the 8 W2 L2-loads/q a 256-cy lookahead.
__global__ __launch_bounds__(256) void causal_kernel(
    const float* __restrict__ pi, const float* __restrict__ pj,
    const float* __restrict__ W2, const float* __restrict__ b2,
    const float* __restrict__ W3, const float* __restrict__ b3,
    float* __restrict__ out)
{
    const int i  = blockIdx.x;
    const int j0 = blockIdx.y * 16;
    const int t  = threadIdx.x;         // 0..255
    const int qt   = t >> 6;            // 0..3 (wave id = h-quarter)
    const int lane = t & 63;
    const int jq   = lane >> 4;         // 0..3
    const int cc   = lane & 15;         // 0..15

    __shared__ float smem[32*16*16];    // 32 KB union
    __shared__ float red[2][16];
    float (*hb)[16]       = (float(*)[16])smem;      // [256][16]
    float (*part)[16][16] = (float(*)[16][16])smem;  // [32][16][16]

    // ---- stage: data-quad d of row t stored at quad-position d^(t&3) ----
    {
        const float p_i = pi[i*HH + t];
        float v[16];
        #pragma unroll
        for (int jj = 0; jj < 16; ++jj)
            v[jj] = fmaxf(p_i + pj[(j0 + jj)*HH + t], 0.f);
        const int sx = t & 3;
        #pragma unroll
        for (int d = 0; d < 4; ++d) {
            float4 w; w.x = v[d*4]; w.y = v[d*4+1]; w.z = v[d*4+2]; w.w = v[d*4+3];
            *(float4*)&hb[t][((d ^ sx) << 2)] = w;
        }
    }
    __syncthreads();

    // ---- inner: 64 h per wave; acc[4 j][8 c] per lane ----
    float acc[4][8];
    #pragma unroll
    for (int jv = 0; jv < 4; ++jv)
        #pragma unroll
        for (int u = 0; u < 8; ++u) acc[jv][u] = 0.f;

    const float* __restrict__ w2p = W2 + cc;
    const int hbase = qt << 6;
    #pragma unroll 4
    for (int q = 0; q < 64; ++q) {
        const int hq = hbase + q;
        const float4 hv = *(const float4*)&hb[hq][((jq ^ (hq & 3)) << 2)];
        const float hvv[4] = {hv.x, hv.y, hv.z, hv.w};
        float wu[8];
        #pragma unroll
        for (int u = 0; u < 8; ++u) wu[u] = w2p[hq*H2 + u*16];
        #pragma unroll
        for (int u = 0; u < 8; ++u)
            #pragma unroll
            for (int jv = 0; jv < 4; ++jv)
                acc[jv][u] = fmaf(hvv[jv], wu[u], acc[jv][u]);
    }
    __syncthreads();            // hb reads complete before overwrite

    // ---- partials: part[qt*8+u][jq*4+jv][cc] ----
    #pragma unroll
    for (int u = 0; u < 8; ++u)
        #pragma unroll
        for (int jv = 0; jv < 4; ++jv)
            part[(qt << 3) + u][(jq << 2) + jv][cc] = acc[jv][u];
    __syncthreads();

    // ---- epilogue: sum quarters, bias+relu, layer-3 dot over 128 c ----
    if (t < 128) {
        const int c  = t;
        const int ce = c & 15;
        const int ue = c >> 4;
        const float b2c = b2[c];
        const float w3c = W3[c];
        float y[16];
        #pragma unroll
        for (int jj = 0; jj < 16; ++jj) {
            const float s = part[0*8 + ue][jj][ce] + part[1*8 + ue][jj][ce]
                          + part[2*8 + ue][jj][ce] + part[3*8 + ue][jj][ce];
            y[jj] = fmaxf(s + b2c, 0.f) * w3c;
        }
        #pragma unroll
        for (int jj = 0; jj < 16; ++jj) {
            float s = y[jj];
            #pragma unroll
            for (int off = 32; off; off >>= 1) s += __shfl_down(s, off, 64);
            if ((t & 63) == 0) red[t >> 6][jj] = s;
        }
    }
    __syncthreads();
    if (t < 16) {
        const int j = j0 + t;
        const float s = red[0][t] + red[1][t] + b3[0];
        out[i*NN + j] = (i == j) ? 0.f : 1.f / (1.f + __expf(-s));
    }
}

// ---------------- Kernel C: conf [96,96,96] ----------------
// grid (96,8) = 768 blocks = 3/CU exact. 192 threads: pair = t>>2 gives
// jg = pair/24 (2 j-groups x 6 j) and kp = pair%24 (k-quad); hq = t&3
// (h-quarter of 64, combined at the end by shfl_xor 1,2 - same wave always).
// Per 4-h chunk: 288 VALU inst vs 6 LDS-b128 + 4 VMEM -> VALU-bound (5:1).
// h-quarters offset by +4 floats in LDS so the 8 distinct broadcast
// addresses hit distinct bank groups (<=2-way aliasing = free).
#define CROW 268   /* 256 + 4*3 gaps; 268*4B = 16-byte multiple */
__global__ __launch_bounds__(192) void conf_kernel(
    const float* __restrict__ ta, const float* __restrict__ tb,
    const float* __restrict__ tcT, const float* __restrict__ V2,
    const float* __restrict__ c2, float* __restrict__ out)
{
    const int i  = blockIdx.x;
    const int j0 = blockIdx.y * 12;
    const int t  = threadIdx.x;         // 0..191
    const int hq = t & 3;               // h-quarter
    const int pr = t >> 2;              // 0..47
    const int jg = pr / 24;             // 0..1
    const int kp = pr % 24;             // 0..23
    const int k0 = kp * 4;

    __shared__ float sbuf[12][CROW];    // ~12.6 KB

    // ---- stage s[jj][h] at col h + 4*(h>>6) (quarter-offset layout) ----
    for (int idx = t; idx < 12*64; idx += 192) {
        const int jj = idx >> 6;
        const int h4 = (idx & 63) << 2;
        const float4 a = *(const float4*)&ta[i*HH + h4];
        const float4 b = *(const float4*)&tb[(j0 + jj)*HH + h4];
        float4 s; s.x = a.x + b.x; s.y = a.y + b.y; s.z = a.z + b.z; s.w = a.w + b.w;
        *(float4*)&sbuf[jj][h4 + 4*(h4 >> 6)] = s;
    }
    __syncthreads();

    float acc[6][4];
    #pragma unroll
    for (int m = 0; m < 6; ++m)
        #pragma unroll
        for (int x = 0; x < 4; ++x) acc[m][x] = 0.f;

    const int hbase = hq << 6;          // 0,64,128,192
    // per-thread row pointers: col(h) = h + 4*hq for h in this quarter
    const float* __restrict__ sb[6];
    #pragma unroll
    for (int m = 0; m < 6; ++m) sb[m] = &sbuf[jg*6 + m][hbase + 4*hq];
    const float* __restrict__ tp = tcT + hbase*NN + k0;
    const float* __restrict__ vp = V2 + hbase;

    #pragma unroll 2
    for (int hc = 0; hc < 64; hc += 4) {
        const float4 t0 = *(const float4*)&tp[(hc+0)*NN];
        const float4 t1 = *(const float4*)&tp[(hc+1)*NN];
        const float4 t2 = *(const float4*)&tp[(hc+2)*NN];
        const float4 t3 = *(const float4*)&tp[(hc+3)*NN];
        const float4 vv = *(const float4*)&vp[hc];
        float4 sm[6];
        #pragma unroll
        for (int m = 0; m < 6; ++m) sm[m] = *(const float4*)&sb[m][hc];

        const float tk[4][4] = {{t0.x,t0.y,t0.z,t0.w},
                                {t1.x,t1.y,t1.z,t1.w},
                                {t2.x,t2.y,t2.z,t2.w},
                                {t3.x,t3.y,t3.z,t3.w}};
        const float vvv[4] = {vv.x, vv.y, vv.z, vv.w};
        #pragma unroll
        for (int m = 0; m < 6; ++m) {
            const float smv[4] = {sm[m].x, sm[m].y, sm[m].z, sm[m].w};
            #pragma unroll
            for (int u = 0; u < 4; ++u) {
                acc[m][0] = fmaf(fmaxf(smv[u] + tk[u][0], 0.f), vvv[u], acc[m][0]);
                acc[m][1] = fmaf(fmaxf(smv[u] + tk[u][1], 0.f), vvv[u], acc[m][1]);
                acc[m][2] = fmaf(fmaxf(smv[u] + tk[u][2], 0.f), vvv[u], acc[m][2]);
                acc[m][3] = fmaf(fmaxf(smv[u] + tk[u][3], 0.f), vvv[u], acc[m][3]);
            }
        }
    }

    // ---- combine the 4 h-quarters (lanes t^1, t^2: same wave) ----
    #pragma unroll
    for (int m = 0; m < 6; ++m)
        #pragma unroll
        for (int x = 0; x < 4; ++x) {
            acc[m][x] += __shfl_xor(acc[m][x], 1, 64);
            acc[m][x] += __shfl_xor(acc[m][x], 2, 64);
        }

    if (hq == 0) {
        const float c2v = c2[0];
        #pragma unroll
        for (int m = 0; m < 6; ++m) {
            const int j = j0 + jg*6 + m;
            float4 o;
            o.x = 1.f / (1.f + __expf(-(acc[m][0] + c2v)));
            o.y = 1.f / (1.f + __expf(-(acc[m][1] + c2v)));
            o.z = 1.f / (1.f + __expf(-(acc[m][2] + c2v)));
            o.w = 1.f / (1.f + __expf(-(acc[m][3] + c2v)));
            if (i == j || i == k0   || j == k0  ) o.x = 0.f;
            if (i == j || i == k0+1 || j == k0+1) o.y = 0.f;
            if (i == j || i == k0+2 || j == k0+2) o.z = 0.f;
            if (i == j || i == k0+3 || j == k0+3) o.w = 0.f;
            *(float4*)&out[(i*NN + j)*NN + k0] = o;
        }
    }
}

extern "C" void kernel_launch(void* const* d_in, const int* in_sizes, int n_in,
                              void* d_out, int out_size, void* d_ws, size_t ws_size,
                              hipStream_t stream) {
    const float* X  = (const float*)d_in[0];
    // d_in[1] = edge_index (unused by reference)
    const float* W1 = (const float*)d_in[2];
    const float* b1 = (const float*)d_in[3];
    const float* W2 = (const float*)d_in[4];
    const float* b2 = (const float*)d_in[5];
    const float* W3 = (const float*)d_in[6];
    const float* b3 = (const float*)d_in[7];
    const float* V1 = (const float*)d_in[8];
    const float* c1 = (const float*)d_in[9];
    const float* V2 = (const float*)d_in[10];
    const float* c2 = (const float*)d_in[11];

    float* out = (float*)d_out;
    float* ws  = (float*)d_ws;
    float* pi  = ws;                 // 96*256
    float* pj  = pi + NN*HH;
    float* ta  = pj + NN*HH;
    float* tb  = ta + NN*HH;
    float* tcT = tb + NN*HH;         // 256*96

    proj_kernel<<<NN, 256, 0, stream>>>(X, W1, b1, V1, c1, pi, pj, ta, tb, tcT);
    causal_kernel<<<dim3(NN, 6), 256, 0, stream>>>(pi, pj, W2, b2, W3, b3, out);
    conf_kernel<<<dim3(NN, 8), 192, 0, stream>>>(ta, tb, tcT, V2, c2, out + NN*NN);
}

// Round 7
// 47.842 us; speedup vs baseline: 1.2396x; 1.2396x over previous
//
#include <hip/hip_runtime.h>
#include <hip/hip_bf16.h>

#define NN 96
#define DD 64
#define HH 256
#define H2 128

// ---------------- Kernel A: projections (round-2 proven form) ----------------
__global__ __launch_bounds__(256) void proj_kernel(
    const float* __restrict__ X, const float* __restrict__ W1, const float* __restrict__ b1,
    const float* __restrict__ V1, const float* __restrict__ c1,
    float* __restrict__ pi, float* __restrict__ pj,
    float* __restrict__ ta, float* __restrict__ tb, float* __restrict__ tcT)
{
    const int i = blockIdx.x;
    const int h = threadIdx.x;          // 0..255
    __shared__ float xs[DD];
    if (h < DD) xs[h] = X[i*DD + h];
    __syncthreads();
    float aPi = 0.f, aPj = 0.f, aTa = 0.f, aTb = 0.f, aTc = 0.f;
    #pragma unroll 8
    for (int d = 0; d < DD; ++d) {
        const float x = xs[d];
        aPi = fmaf(x, W1[d*HH + h],          aPi);
        aPj = fmaf(x, W1[(DD + d)*HH + h],   aPj);
        aTa = fmaf(x, V1[d*HH + h],          aTa);
        aTb = fmaf(x, V1[(DD + d)*HH + h],   aTb);
        aTc = fmaf(x, V1[(2*DD + d)*HH + h], aTc);
    }
    pi[i*HH + h] = aPi + b1[h];
    pj[i*HH + h] = aPj;
    ta[i*HH + h] = aTa + c1[h];
    tb[i*HH + h] = aTb;
    tcT[h*NN + i] = aTc;
}

// ---------------- Fused kernel: causal (by<8) + conf (by>=8) ----------------
// Inner loops are round-2-exact (proven best). Fusion co-schedules causal's
// DS/L2-heavy blocks with conf's VALU/latency-bound blocks on every CU:
// grid (96,16) = 1536 blocks, union LDS 24.7 KB -> exactly 6 blocks/CU,
// all blocks co-resident -> causal hides under conf's stalls, one launch
// gap removed.
__global__ __launch_bounds__(256) void fused_kernel(
    const float* __restrict__ pi, const float* __restrict__ pj,
    const float* __restrict__ W2, const float* __restrict__ b2,
    const float* __restrict__ W3, const float* __restrict__ b3,
    const float* __restrict__ ta, const float* __restrict__ tb,
    const float* __restrict__ tcT, const float* __restrict__ V2,
    const float* __restrict__ c2, float* __restrict__ out)
{
    __shared__ float smem[4*64*2*12 + 2*12];   // 6168 floats: causal(6144+24) / conf(3072)
    const int i  = blockIdx.x;
    const int by = blockIdx.y;
    const int t  = threadIdx.x;         // 0..255

    if (by < 8) {
        // ================= causal path (round-2 exact) =================
        const int j0 = by * 12;
        const int c2c = t & 63;
        const int qt  = t >> 6;         // 0..3

        float (*hb)[12]          = (float(*)[12])smem;          // [256][12]
        float (*part)[64][2][12] = (float(*)[64][2][12])smem;   // [4][64][2][12]
        float (*red)[12]         = (float(*)[12])(smem + 6144); // [2][12]

        // ---- stage hbT[h][jj] = relu(pi[i][h] + pj[j][h]), h = t ----
        {
            const float p_i = pi[i*HH + t];
            #pragma unroll
            for (int jj = 0; jj < 12; ++jj)
                hb[t][jj] = fmaxf(p_i + pj[(j0 + jj)*HH + t], 0.f);
        }
        __syncthreads();

        float acc0[12], acc1[12];
        #pragma unroll
        for (int jj = 0; jj < 12; ++jj) { acc0[jj] = 0.f; acc1[jj] = 0.f; }

        const float* __restrict__ w2p = W2 + (qt*64)*H2 + c2c;
        #pragma unroll 2
        for (int q = 0; q < 64; ++q) {
            const float wa = w2p[q*H2];
            const float wb = w2p[q*H2 + 64];
            const int hq = qt*64 + q;
            const float4 hA = *(const float4*)&hb[hq][0];
            const float4 hB = *(const float4*)&hb[hq][4];
            const float4 hC = *(const float4*)&hb[hq][8];
            const float hv[12] = {hA.x,hA.y,hA.z,hA.w, hB.x,hB.y,hB.z,hB.w, hC.x,hC.y,hC.z,hC.w};
            #pragma unroll
            for (int jj = 0; jj < 12; ++jj) {
                acc0[jj] = fmaf(hv[jj], wa, acc0[jj]);
                acc1[jj] = fmaf(hv[jj], wb, acc1[jj]);
            }
        }
        __syncthreads();          // all hb reads done before overwrite

        // ---- partials: part[qt][c2][cc][jj] ----
        #pragma unroll
        for (int b = 0; b < 3; ++b) {
            float4 p0, p1;
            p0.x = acc0[b*4+0]; p0.y = acc0[b*4+1]; p0.z = acc0[b*4+2]; p0.w = acc0[b*4+3];
            p1.x = acc1[b*4+0]; p1.y = acc1[b*4+1]; p1.z = acc1[b*4+2]; p1.w = acc1[b*4+3];
            *(float4*)&part[qt][c2c][0][b*4] = p0;
            *(float4*)&part[qt][c2c][1][b*4] = p1;
        }
        __syncthreads();

        // ---- reduce quarters, layer2 bias+relu, layer3 dot over 128 c ----
        if (t < 128) {
            const int c  = t;
            const int cl = t & 63;
            const int cc = t >> 6;
            const float b2c = b2[c];
            const float w3c = W3[c];
            float v[12];
            #pragma unroll
            for (int b = 0; b < 3; ++b) {
                float4 s; s.x = 0.f; s.y = 0.f; s.z = 0.f; s.w = 0.f;
                #pragma unroll
                for (int qq = 0; qq < 4; ++qq) {
                    const float4 p = *(const float4*)&part[qq][cl][cc][b*4];
                    s.x += p.x; s.y += p.y; s.z += p.z; s.w += p.w;
                }
                v[b*4+0] = fmaxf(s.x + b2c, 0.f) * w3c;
                v[b*4+1] = fmaxf(s.y + b2c, 0.f) * w3c;
                v[b*4+2] = fmaxf(s.z + b2c, 0.f) * w3c;
                v[b*4+3] = fmaxf(s.w + b2c, 0.f) * w3c;
            }
            #pragma unroll
            for (int jj = 0; jj < 12; ++jj) {
                float s = v[jj];
                #pragma unroll
                for (int off = 32; off; off >>= 1) s += __shfl_down(s, off, 64);
                if ((t & 63) == 0) red[t >> 6][jj] = s;
            }
        }
        __syncthreads();
        if (t < 12) {
            const int j = j0 + t;
            const float s = red[0][t] + red[1][t] + b3[0];
            out[i*NN + j] = (i == j) ? 0.f : 1.f / (1.f + __expf(-s));
        }
    } else {
        // ================= conf path (round-2 exact inner) =================
        const int j0 = (by - 8) * 12;
        float (*sbuf)[HH] = (float(*)[HH])smem;     // [12][256]
        float* outc = out + NN*NN;

        // ---- stage s[jj][h] = ta[i][h] + tb[j][h] (all 256 threads) ----
        for (int idx = t; idx < 12*HH/4; idx += 256) {
            const int jj = idx >> 6;            // 64 float4s per row
            const int h4 = (idx & 63) << 2;
            const float4 a = *(const float4*)&ta[i*HH + h4];
            const float4 b = *(const float4*)&tb[(j0 + jj)*HH + h4];
            float4 s; s.x = a.x + b.x; s.y = a.y + b.y; s.z = a.z + b.z; s.w = a.w + b.w;
            *(float4*)&sbuf[jj][h4] = s;
        }
        __syncthreads();

        if (t < 192) {
            const int g  = t / 48;              // j-group 0..3
            const int l  = t % 48;              // k-pair lane
            const int k0 = 2*l;

            float acc[3][2];
            #pragma unroll
            for (int m = 0; m < 3; ++m) { acc[m][0] = 0.f; acc[m][1] = 0.f; }

            const float* __restrict__ sb0 = &sbuf[g*3 + 0][0];
            const float* __restrict__ sb1 = &sbuf[g*3 + 1][0];
            const float* __restrict__ sb2 = &sbuf[g*3 + 2][0];

            #pragma unroll 2
            for (int h0 = 0; h0 < HH; h0 += 4) {
                const float2 t0 = *(const float2*)&tcT[(h0+0)*NN + k0];
                const float2 t1 = *(const float2*)&tcT[(h0+1)*NN + k0];
                const float2 t2 = *(const float2*)&tcT[(h0+2)*NN + k0];
                const float2 t3 = *(const float2*)&tcT[(h0+3)*NN + k0];
                const float4 va = *(const float4*)&V2[h0];        // uniform -> scalar
                const float4 sA = *(const float4*)&sb0[h0];
                const float4 sB = *(const float4*)&sb1[h0];
                const float4 sC = *(const float4*)&sb2[h0];
                const float s[3][4] = {{sA.x,sA.y,sA.z,sA.w},
                                       {sB.x,sB.y,sB.z,sB.w},
                                       {sC.x,sC.y,sC.z,sC.w}};
                const float tc[4][2] = {{t0.x,t0.y},{t1.x,t1.y},
                                        {t2.x,t2.y},{t3.x,t3.y}};
                const float vv[4] = {va.x,va.y,va.z,va.w};
                #pragma unroll
                for (int u4 = 0; u4 < 4; ++u4) {
                    #pragma unroll
                    for (int m = 0; m < 3; ++m) {
                        acc[m][0] = fmaf(fmaxf(s[m][u4] + tc[u4][0], 0.f), vv[u4], acc[m][0]);
                        acc[m][1] = fmaf(fmaxf(s[m][u4] + tc[u4][1], 0.f), vv[u4], acc[m][1]);
                    }
                }
            }

            const float c2v = c2[0];
            #pragma unroll
            for (int m = 0; m < 3; ++m) {
                const int j = j0 + g*3 + m;
                float2 o;
                o.x = 1.f / (1.f + __expf(-(acc[m][0] + c2v)));
                o.y = 1.f / (1.f + __expf(-(acc[m][1] + c2v)));
                if (i == j || i == k0   || j == k0  ) o.x = 0.f;
                if (i == j || i == k0+1 || j == k0+1) o.y = 0.f;
                *(float2*)&outc[(i*NN + j)*NN + k0] = o;
            }
        }
    }
}

extern "C" void kernel_launch(void* const* d_in, const int* in_sizes, int n_in,
                              void* d_out, int out_size, void* d_ws, size_t ws_size,
                              hipStream_t stream) {
    const float* X  = (const float*)d_in[0];
    // d_in[1] = edge_index (unused by reference)
    const float* W1 = (const float*)d_in[2];
    const float* b1 = (const float*)d_in[3];
    const float* W2 = (const float*)d_in[4];
    const float* b2 = (const float*)d_in[5];
    const float* W3 = (const float*)d_in[6];
    const float* b3 = (const float*)d_in[7];
    const float* V1 = (const float*)d_in[8];
    const float* c1 = (const float*)d_in[9];
    const float* V2 = (const float*)d_in[10];
    const float* c2 = (const float*)d_in[11];

    float* out = (float*)d_out;
    float* ws  = (float*)d_ws;
    float* pi  = ws;                 // 96*256
    float* pj  = pi + NN*HH;
    float* ta  = pj + NN*HH;
    float* tb  = ta + NN*HH;
    float* tcT = tb + NN*HH;         // 256*96

    proj_kernel<<<NN, 256, 0, stream>>>(X, W1, b1, V1, c1, pi, pj, ta, tb, tcT);
    fused_kernel<<<dim3(NN, 16), 256, 0, stream>>>(pi, pj, W2, b2, W3, b3,
                                                   ta, tb, tcT, V2, c2, out);
}

// Round 8
// 40.876 us; speedup vs baseline: 1.4509x; 1.1704x over previous
//
#include <hip/hip_runtime.h>
#include <hip/hip_bf16.h>

#define NN 96
#define DD 64
#define HH 256
#define H2 128

typedef float v2f __attribute__((ext_vector_type(2)));

// ---------------- Kernel A: projections ----------------
// Same as round-2 except tc is written in h-PAIRED layout:
// tcP[((h>>1)*NN + k)*2 + (h&1)] = {tc[h even], tc[h odd]} pairs per (hp, k),
// so conf can load float2 h-pairs (and float4 = 2 k of pairs) for packed math.
__global__ __launch_bounds__(256) void proj_kernel(
    const float* __restrict__ X, const float* __restrict__ W1, const float* __restrict__ b1,
    const float* __restrict__ V1, const float* __restrict__ c1,
    float* __restrict__ pi, float* __restrict__ pj,
    float* __restrict__ ta, float* __restrict__ tb, float* __restrict__ tcP)
{
    const int i = blockIdx.x;
    const int h = threadIdx.x;          // 0..255
    __shared__ float xs[DD];
    if (h < DD) xs[h] = X[i*DD + h];
    __syncthreads();
    float aPi = 0.f, aPj = 0.f, aTa = 0.f, aTb = 0.f, aTc = 0.f;
    #pragma unroll 8
    for (int d = 0; d < DD; ++d) {
        const float x = xs[d];
        aPi = fmaf(x, W1[d*HH + h],          aPi);
        aPj = fmaf(x, W1[(DD + d)*HH + h],   aPj);
        aTa = fmaf(x, V1[d*HH + h],          aTa);
        aTb = fmaf(x, V1[(DD + d)*HH + h],   aTb);
        aTc = fmaf(x, V1[(2*DD + d)*HH + h], aTc);
    }
    pi[i*HH + h] = aPi + b1[h];
    pj[i*HH + h] = aPj;
    ta[i*HH + h] = aTa + c1[h];
    tb[i*HH + h] = aTb;
    tcP[((h >> 1)*NN + i)*2 + (h & 1)] = aTc;
}

// ---------------- Fused kernel: causal (by<8) + conf (by>=8) ----------------
// R7 fused structure (proven win) with packed-f32 inner loops:
// v_pk_fma_f32/v_pk_add_f32 are full-rate 2xf32 on CDNA4 (the 157.3 TF spec
// = 2x the scalar 78.6 TF rate). causal packs over jj-pairs; conf packs over
// h-pairs (tcP layout), which also halves conf's tc VMEM to 2 coalesced
// b128 per 4-h chunk.
__global__ __launch_bounds__(256) void fused_kernel(
    const float* __restrict__ pi, const float* __restrict__ pj,
    const float* __restrict__ W2, const float* __restrict__ b2,
    const float* __restrict__ W3, const float* __restrict__ b3,
    const float* __restrict__ ta, const float* __restrict__ tb,
    const float* __restrict__ tcP, const float* __restrict__ V2,
    const float* __restrict__ c2, float* __restrict__ out)
{
    __shared__ float smem[4*64*2*12 + 2*12];   // causal(6144+24) / conf(3072)
    const int i  = blockIdx.x;
    const int by = blockIdx.y;
    const int t  = threadIdx.x;         // 0..255

    if (by < 8) {
        // ================= causal path (pk over jj-pairs) =================
        const int j0 = by * 12;
        const int c2c = t & 63;
        const int qt  = t >> 6;         // 0..3

        float (*hb)[12]          = (float(*)[12])smem;          // [256][12]
        float (*part)[64][2][12] = (float(*)[64][2][12])smem;   // [4][64][2][12]
        float (*red)[12]         = (float(*)[12])(smem + 6144); // [2][12]

        // ---- stage hbT[h][jj] = relu(pi[i][h] + pj[j][h]), h = t ----
        {
            const float p_i = pi[i*HH + t];
            #pragma unroll
            for (int jj = 0; jj < 12; ++jj)
                hb[t][jj] = fmaxf(p_i + pj[(j0 + jj)*HH + t], 0.f);
        }
        __syncthreads();

        v2f acc0[6], acc1[6];
        #pragma unroll
        for (int p = 0; p < 6; ++p) { acc0[p] = (v2f)(0.f); acc1[p] = (v2f)(0.f); }

        const float* __restrict__ w2p = W2 + (qt*64)*H2 + c2c;
        #pragma unroll 2
        for (int q = 0; q < 64; ++q) {
            const float wa = w2p[q*H2];
            const float wb = w2p[q*H2 + 64];
            const v2f wa2 = {wa, wa};
            const v2f wb2 = {wb, wb};
            const int hq = qt*64 + q;
            const float4 hA = *(const float4*)&hb[hq][0];
            const float4 hB = *(const float4*)&hb[hq][4];
            const float4 hC = *(const float4*)&hb[hq][8];
            const v2f hp[6] = {{hA.x,hA.y},{hA.z,hA.w},
                               {hB.x,hB.y},{hB.z,hB.w},
                               {hC.x,hC.y},{hC.z,hC.w}};
            #pragma unroll
            for (int p = 0; p < 6; ++p) {
                acc0[p] += hp[p] * wa2;     // contracts to v_pk_fma_f32
                acc1[p] += hp[p] * wb2;
            }
        }
        __syncthreads();          // all hb reads done before overwrite

        // ---- partials: part[qt][c2][cc][jj] ----
        #pragma unroll
        for (int b = 0; b < 3; ++b) {
            float4 p0, p1;
            p0.x = acc0[b*2].x; p0.y = acc0[b*2].y; p0.z = acc0[b*2+1].x; p0.w = acc0[b*2+1].y;
            p1.x = acc1[b*2].x; p1.y = acc1[b*2].y; p1.z = acc1[b*2+1].x; p1.w = acc1[b*2+1].y;
            *(float4*)&part[qt][c2c][0][b*4] = p0;
            *(float4*)&part[qt][c2c][1][b*4] = p1;
        }
        __syncthreads();

        // ---- reduce quarters, layer2 bias+relu, layer3 dot over 128 c ----
        if (t < 128) {
            const int c  = t;
            const int cl = t & 63;
            const int cc = t >> 6;
            const float b2c = b2[c];
            const float w3c = W3[c];
            float v[12];
            #pragma unroll
            for (int b = 0; b < 3; ++b) {
                float4 s; s.x = 0.f; s.y = 0.f; s.z = 0.f; s.w = 0.f;
                #pragma unroll
                for (int qq = 0; qq < 4; ++qq) {
                    const float4 p = *(const float4*)&part[qq][cl][cc][b*4];
                    s.x += p.x; s.y += p.y; s.z += p.z; s.w += p.w;
                }
                v[b*4+0] = fmaxf(s.x + b2c, 0.f) * w3c;
                v[b*4+1] = fmaxf(s.y + b2c, 0.f) * w3c;
                v[b*4+2] = fmaxf(s.z + b2c, 0.f) * w3c;
                v[b*4+3] = fmaxf(s.w + b2c, 0.f) * w3c;
            }
            #pragma unroll
            for (int jj = 0; jj < 12; ++jj) {
                float s = v[jj];
                #pragma unroll
                for (int off = 32; off; off >>= 1) s += __shfl_down(s, off, 64);
                if ((t & 63) == 0) red[t >> 6][jj] = s;
            }
        }
        __syncthreads();
        if (t < 12) {
            const int j = j0 + t;
            const float s = red[0][t] + red[1][t] + b3[0];
            out[i*NN + j] = (i == j) ? 0.f : 1.f / (1.f + __expf(-s));
        }
    } else {
        // ================= conf path (pk over h-pairs) =================
        const int j0 = (by - 8) * 12;
        float (*sbuf)[HH] = (float(*)[HH])smem;     // [12][256]
        float* outc = out + NN*NN;

        // ---- stage s[jj][h] = ta[i][h] + tb[j][h] (all 256 threads) ----
        for (int idx = t; idx < 12*HH/4; idx += 256) {
            const int jj = idx >> 6;            // 64 float4s per row
            const int h4 = (idx & 63) << 2;
            const float4 a = *(const float4*)&ta[i*HH + h4];
            const float4 b = *(const float4*)&tb[(j0 + jj)*HH + h4];
            float4 s; s.x = a.x + b.x; s.y = a.y + b.y; s.z = a.z + b.z; s.w = a.w + b.w;
            *(float4*)&sbuf[jj][h4] = s;
        }
        __syncthreads();

        if (t < 192) {
            const int g  = t / 48;              // j-group 0..3
            const int l  = t % 48;              // k-pair lane
            const int k0 = 2*l;

            v2f acc[3][2];                      // [m][kk], packed over h-pair
            #pragma unroll
            for (int m = 0; m < 3; ++m) { acc[m][0] = (v2f)(0.f); acc[m][1] = (v2f)(0.f); }

            const float* __restrict__ sb0 = &sbuf[g*3 + 0][0];
            const float* __restrict__ sb1 = &sbuf[g*3 + 1][0];
            const float* __restrict__ sb2 = &sbuf[g*3 + 2][0];

            #pragma unroll 2
            for (int h0 = 0; h0 < HH; h0 += 4) {
                // tA = {tc[h0][k0], tc[h0+1][k0], tc[h0][k0+1], tc[h0+1][k0+1]}
                const float4 tA = *(const float4*)&tcP[((h0 >> 1)    *NN + k0)*2];
                const float4 tB = *(const float4*)&tcP[(((h0 >> 1)+1)*NN + k0)*2];
                const float4 vv = *(const float4*)&V2[h0];        // uniform
                const float4 sA = *(const float4*)&sb0[h0];
                const float4 sB = *(const float4*)&sb1[h0];
                const float4 sC = *(const float4*)&sb2[h0];
                const v2f va01 = {vv.x, vv.y}, va23 = {vv.z, vv.w};
                const v2f tk0a = {tA.x, tA.y}, tk1a = {tA.z, tA.w};
                const v2f tk0b = {tB.x, tB.y}, tk1b = {tB.z, tB.w};
                const v2f sp[3][2] = {{{sA.x,sA.y},{sA.z,sA.w}},
                                      {{sB.x,sB.y},{sB.z,sB.w}},
                                      {{sC.x,sC.y},{sC.z,sC.w}}};
                #pragma unroll
                for (int m = 0; m < 3; ++m) {
                    v2f x;
                    x = sp[m][0] + tk0a;                    // v_pk_add_f32
                    x.x = fmaxf(x.x, 0.f); x.y = fmaxf(x.y, 0.f);
                    acc[m][0] += x * va01;                  // v_pk_fma_f32
                    x = sp[m][0] + tk1a;
                    x.x = fmaxf(x.x, 0.f); x.y = fmaxf(x.y, 0.f);
                    acc[m][1] += x * va01;
                    x = sp[m][1] + tk0b;
                    x.x = fmaxf(x.x, 0.f); x.y = fmaxf(x.y, 0.f);
                    acc[m][0] += x * va23;
                    x = sp[m][1] + tk1b;
                    x.x = fmaxf(x.x, 0.f); x.y = fmaxf(x.y, 0.f);
                    acc[m][1] += x * va23;
                }
            }

            const float c2v = c2[0];
            #pragma unroll
            for (int m = 0; m < 3; ++m) {
                const int j = j0 + g*3 + m;
                const float a0 = acc[m][0].x + acc[m][0].y;
                const float a1 = acc[m][1].x + acc[m][1].y;
                float2 o;
                o.x = 1.f / (1.f + __expf(-(a0 + c2v)));
                o.y = 1.f / (1.f + __expf(-(a1 + c2v)));
                if (i == j || i == k0   || j == k0  ) o.x = 0.f;
                if (i == j || i == k0+1 || j == k0+1) o.y = 0.f;
                *(float2*)&outc[(i*NN + j)*NN + k0] = o;
            }
        }
    }
}

extern "C" void kernel_launch(void* const* d_in, const int* in_sizes, int n_in,
                              void* d_out, int out_size, void* d_ws, size_t ws_size,
                              hipStream_t stream) {
    const float* X  = (const float*)d_in[0];
    // d_in[1] = edge_index (unused by reference)
    const float* W1 = (const float*)d_in[2];
    const float* b1 = (const float*)d_in[3];
    const float* W2 = (const float*)d_in[4];
    const float* b2 = (const float*)d_in[5];
    const float* W3 = (const float*)d_in[6];
    const float* b3 = (const float*)d_in[7];
    const float* V1 = (const float*)d_in[8];
    const float* c1 = (const float*)d_in[9];
    const float* V2 = (const float*)d_in[10];
    const float* c2 = (const float*)d_in[11];

    float* out = (float*)d_out;
    float* ws  = (float*)d_ws;
    float* pi  = ws;                 // 96*256
    float* pj  = pi + NN*HH;
    float* ta  = pj + NN*HH;
    float* tb  = ta + NN*HH;
    float* tcP = tb + NN*HH;         // 128*96 float2 = 256*96 floats

    proj_kernel<<<NN, 256, 0, stream>>>(X, W1, b1, V1, c1, pi, pj, ta, tb, tcP);
    fused_kernel<<<dim3(NN, 16), 256, 0, stream>>>(pi, pj, W2, b2, W3, b3,
                                                   ta, tb, tcP, V2, c2, out);
}